// Round 18
// baseline (233.790 us; speedup 1.0000x reference)
//
#include <hip/hip_runtime.h>
#include <hip/hip_bf16.h>
#include <cstddef>

#define NB 4
#define NS 2048
#define NT 2048
#define NE 1024
#define NH 16
#define ND 64
#define NM (NB*NS)   // 8192 rows

typedef __attribute__((ext_vector_type(8))) short short8;
typedef __attribute__((ext_vector_type(4))) float f32x4;
typedef __attribute__((ext_vector_type(16))) float f32x16;
typedef __attribute__((ext_vector_type(4))) unsigned short us4;
typedef __attribute__((ext_vector_type(8))) unsigned short us8;

__device__ __forceinline__ unsigned short f2bf(float f) {
    union { float f; unsigned u; } v; v.f = f;
    unsigned r = v.u + 0x7fffu + ((v.u >> 16) & 1u);
    return (unsigned short)(r >> 16);
}

// packed pair f32->bf16: native v_cvt_pk_bf16_f32 (no builtin on gfx950)
__device__ __forceinline__ unsigned pkbf(float a, float b) {
    unsigned r;
    asm("v_cvt_pk_bf16_f32 %0, %1, %2" : "=v"(r) : "v"(a), "v"(b));
    return r;
}

// async global->LDS, 16B per lane. LDS dest = wave-uniform base + lane*16.
__device__ __forceinline__ void gl16(const void* g, void* l) {
    __builtin_amdgcn_global_load_lds(
        (const __attribute__((address_space(1))) unsigned int*)g,
        (__attribute__((address_space(3))) unsigned int*)l,
        16, 0, 0);
}

// ---------------------------------------------------------------------------
// fp32 -> bf16 bulk convert (vectorized, grid-stride)
// ---------------------------------------------------------------------------
__global__ void cvt_bf16(const float* __restrict__ src,
                         unsigned short* __restrict__ dst, int n4)
{
    int i = blockIdx.x * blockDim.x + threadIdx.x;
    int stride = gridDim.x * blockDim.x;
    for (; i < n4; i += stride) {
        float4 v = ((const float4*)src)[i];
        us4 o;
        o[0] = f2bf(v.x); o[1] = f2bf(v.y); o[2] = f2bf(v.z); o[3] = f2bf(v.w);
        ((us4*)dst)[i] = o;
    }
}

// ---------------------------------------------------------------------------
// Wq/Wk/Wv [16][1024][64] fp32 -> WcT bf16 [3072][1024]  (B^T layout)
// ---------------------------------------------------------------------------
__global__ __launch_bounds__(256)
void wqkv_prep(const float* __restrict__ Wq, const float* __restrict__ Wk,
               const float* __restrict__ Wv, unsigned short* __restrict__ WcT)
{
    __shared__ float Ts[64][65];
    const int p = blockIdx.y;            // 0..47
    const int e0 = blockIdx.x * 64;
    const int j = p >> 4, h = p & 15;
    const float* W = (j == 0 ? Wq : (j == 1 ? Wk : Wv)) + (size_t)h * NE * ND;
    const int t = threadIdx.x;
    #pragma unroll
    for (int l = 0; l < 4; ++l) {
        int e = l * 16 + (t >> 4), d4 = (t & 15) * 4;
        float4 v = *(const float4*)(W + (size_t)(e0 + e) * ND + d4);
        Ts[d4 + 0][e] = v.x; Ts[d4 + 1][e] = v.y;
        Ts[d4 + 2][e] = v.z; Ts[d4 + 3][e] = v.w;
    }
    __syncthreads();
    const int d = t >> 2, c = (t & 3) * 16;
    us8 o0, o1;
    #pragma unroll
    for (int i = 0; i < 8; ++i) {
        o0[i] = f2bf(Ts[d][c + i]);
        o1[i] = f2bf(Ts[d][c + 8 + i]);
    }
    unsigned short* dst = WcT + ((size_t)(p * 64 + d)) * NE + e0 + c;
    *(us8*)dst = o0; *(us8*)(dst + 8) = o1;
}

// ---------------------------------------------------------------------------
// Wo [1024][1024] fp32 -> WoT bf16 [n][e] (transposed)
// ---------------------------------------------------------------------------
__global__ __launch_bounds__(256)
void woT_prep(const float* __restrict__ Wo, unsigned short* __restrict__ WoT)
{
    __shared__ float Ts[64][65];
    const int c0 = blockIdx.x * 64, n0 = blockIdx.y * 64;
    const int t = threadIdx.x;
    #pragma unroll
    for (int l = 0; l < 4; ++l) {
        int c = l * 16 + (t >> 4), n4 = (t & 15) * 4;
        float4 v = *(const float4*)(Wo + (size_t)(c0 + c) * NE + n0 + n4);
        Ts[n4 + 0][c] = v.x; Ts[n4 + 1][c] = v.y;
        Ts[n4 + 2][c] = v.z; Ts[n4 + 3][c] = v.w;
    }
    __syncthreads();
    const int n = t >> 2, cc4 = (t & 3) * 16;
    us8 o0, o1;
    #pragma unroll
    for (int i = 0; i < 8; ++i) {
        o0[i] = f2bf(Ts[n][cc4 + i]);
        o1[i] = f2bf(Ts[n][cc4 + 8 + i]);
    }
    unsigned short* dst = WoT + (size_t)(n0 + n) * NE + c0 + cc4;
    *(us8*)dst = o0; *(us8*)(dst + 8) = o1;
}

__global__ void bias_cat(const float* __restrict__ bq, const float* __restrict__ bk,
                         const float* __restrict__ bv, float* __restrict__ bc)
{
    int i = blockIdx.x * blockDim.x + threadIdx.x;
    if (i < 1024) { bc[i] = bq[i]; bc[1024 + i] = bk[i]; bc[2048 + i] = bv[i]; }
}

// ---------------------------------------------------------------------------
// FUSED QKV projection GEMM (kept from R16, verified: -6 us vs split).
// grid 64x24 = 1536 blocks ~ 6/CU. Block picks A = xb (Q) or yb (K/V).
// BK=64 / gl16 / slot^=row&7 staging (R12-verified).
// ---------------------------------------------------------------------------
__global__ __launch_bounds__(256)
void gemm_qkv(const unsigned short* __restrict__ xb,
              const unsigned short* __restrict__ yb,
              const unsigned short* __restrict__ WcT,
              const float* __restrict__ bias,
              unsigned short* __restrict__ qb, unsigned short* __restrict__ kb,
              unsigned short* __restrict__ vt)
{
    __shared__ __align__(16) unsigned short As[128 * 64];
    __shared__ __align__(16) unsigned short Bs[128 * 64];
    const int m0 = blockIdx.x * 128;
    const int gn0 = blockIdx.y * 128;            // global n offset 0..2944
    const unsigned short* A  = (gn0 < 1024) ? xb : yb;
    const unsigned short* Bt = WcT + (size_t)gn0 * NE;
    const int t = threadIdx.x, l = t & 63, w = t >> 6;
    const int wm = w >> 1, wn = w & 1;
    const int srow = l >> 3;
    const int sslot = (l & 7) ^ (srow & 7);
    const int rl = l & 15;
    const int q = l >> 4;

    const f32x4 fz = {0.f, 0.f, 0.f, 0.f};
    f32x4 acc[4][4];
    #pragma unroll
    for (int i = 0; i < 4; ++i)
        #pragma unroll
        for (int j = 0; j < 4; ++j) acc[i][j] = fz;

    for (int k0 = 0; k0 < NE; k0 += 64) {
        __syncthreads();
        #pragma unroll
        for (int j = 0; j < 4; ++j) {
            int ra = w * 32 + j * 8 + srow;
            gl16(A + (size_t)(m0 + ra) * NE + k0 + sslot * 8,
                 &As[(w * 32 + j * 8) * 64]);
            gl16(Bt + (size_t)ra * NE + k0 + sslot * 8,
                 &Bs[(w * 32 + j * 8) * 64]);
        }
        __syncthreads();
        #pragma unroll
        for (int kk = 0; kk < 2; ++kk) {
            const int fsl = ((kk * 4 + q) ^ (rl & 7)) * 8;
            short8 a[4], b[4];
            #pragma unroll
            for (int mi = 0; mi < 4; ++mi)
                a[mi] = *(const short8*)&As[(wm * 64 + mi * 16 + rl) * 64 + fsl];
            #pragma unroll
            for (int ni = 0; ni < 4; ++ni)
                b[ni] = *(const short8*)&Bs[(wn * 64 + ni * 16 + rl) * 64 + fsl];
            #pragma unroll
            for (int mi = 0; mi < 4; ++mi)
                #pragma unroll
                for (int ni = 0; ni < 4; ++ni)
                    acc[mi][ni] = __builtin_amdgcn_mfma_f32_16x16x32_bf16(
                        a[mi], b[ni], acc[mi][ni], 0, 0, 0);
        }
    }

    const float c1 = 0.18033688011112042f;   // 0.125 * log2(e)
    #pragma unroll
    for (int mi = 0; mi < 4; ++mi) {
        #pragma unroll
        for (int ni = 0; ni < 4; ++ni) {
            int n = gn0 + wn * 64 + ni * 16 + (l & 15);
            float bs = bias[n];
            int j = n >> 10, hh = (n >> 6) & 15, d = n & 63;
            float sc = (j == 0) ? c1 : 1.0f;
            #pragma unroll
            for (int r = 0; r < 4; ++r) {
                int i = m0 + wm * 64 + mi * 16 + (l >> 4) * 4 + r;
                int b = i >> 11, s = i & (NS - 1);
                unsigned short bfv = f2bf((acc[mi][ni][r] + bs) * sc);
                if (j == 0)
                    qb[(((size_t)b * NH + hh) * NS + s) * ND + d] = bfv;
                else if (j == 1)
                    kb[(((size_t)b * NH + hh) * NT + s) * ND + d] = bfv;
                else
                    vt[(((size_t)b * NH + hh) * ND + d) * NT + s] = bfv;
            }
        }
    }
}

// ---------------------------------------------------------------------------
// bf16 MFMA GEMM for output projection (unchanged from R12, verified)
// ---------------------------------------------------------------------------
__global__ __launch_bounds__(256)
void gemm_out(const unsigned short* __restrict__ A,
              const unsigned short* __restrict__ Bt,
              const float* __restrict__ bias, float* __restrict__ C)
{
    __shared__ __align__(16) unsigned short As[128 * 64];
    __shared__ __align__(16) unsigned short Bs[128 * 64];
    const int m0 = blockIdx.x * 128, n0 = blockIdx.y * 128;
    const int t = threadIdx.x, l = t & 63, w = t >> 6;
    const int wm = w >> 1, wn = w & 1;
    const int srow = l >> 3;
    const int sslot = (l & 7) ^ (srow & 7);
    const int rl = l & 15;
    const int q = l >> 4;

    const f32x4 fz = {0.f, 0.f, 0.f, 0.f};
    f32x4 acc[4][4];
    #pragma unroll
    for (int i = 0; i < 4; ++i)
        #pragma unroll
        for (int j = 0; j < 4; ++j) acc[i][j] = fz;

    for (int k0 = 0; k0 < NE; k0 += 64) {
        __syncthreads();
        #pragma unroll
        for (int j = 0; j < 4; ++j) {
            int ra = w * 32 + j * 8 + srow;
            gl16(A + (size_t)(m0 + ra) * NE + k0 + sslot * 8,
                 &As[(w * 32 + j * 8) * 64]);
            gl16(Bt + (size_t)(n0 + ra) * NE + k0 + sslot * 8,
                 &Bs[(w * 32 + j * 8) * 64]);
        }
        __syncthreads();
        #pragma unroll
        for (int kk = 0; kk < 2; ++kk) {
            const int fsl = ((kk * 4 + q) ^ (rl & 7)) * 8;
            short8 a[4], b[4];
            #pragma unroll
            for (int mi = 0; mi < 4; ++mi)
                a[mi] = *(const short8*)&As[(wm * 64 + mi * 16 + rl) * 64 + fsl];
            #pragma unroll
            for (int ni = 0; ni < 4; ++ni)
                b[ni] = *(const short8*)&Bs[(wn * 64 + ni * 16 + rl) * 64 + fsl];
            #pragma unroll
            for (int mi = 0; mi < 4; ++mi)
                #pragma unroll
                for (int ni = 0; ni < 4; ++ni)
                    acc[mi][ni] = __builtin_amdgcn_mfma_f32_16x16x32_bf16(
                        a[mi], b[ni], acc[mi][ni], 0, 0, 0);
        }
    }

    #pragma unroll
    for (int mi = 0; mi < 4; ++mi) {
        #pragma unroll
        for (int ni = 0; ni < 4; ++ni) {
            int n = n0 + wn * 64 + ni * 16 + (l & 15);
            float bs = bias[n];
            #pragma unroll
            for (int r = 0; r < 4; ++r) {
                int i = m0 + wm * 64 + mi * 16 + (l >> 4) * 4 + r;
                C[(size_t)i * NE + n] = acc[mi][ni][r] + bs;
            }
        }
    }
}

// ---------------------------------------------------------------------------
// bf16 MFMA flash attention v4 + T5 setprio (only change vs R17's verified
// 101 us kernel: MFMA clusters wrapped in s_setprio(1)/(0) — m191 evidence:
// +4-7% on attn where independent blocks share a CU at different phases).
// ---------------------------------------------------------------------------
__global__ __launch_bounds__(256)
void flash_mfma(const unsigned short* __restrict__ Q,
                const unsigned short* __restrict__ K,
                const unsigned short* __restrict__ Vt,
                unsigned short* __restrict__ Oc)
{
    __shared__ __align__(16) unsigned short Ks[64][72];
    __shared__ __align__(16) unsigned short Vs[64][72];   // V^T tile: [d][t]
    __shared__ float Ss[4][32];
    const int s0 = blockIdx.x * 128, h = blockIdx.y, b = blockIdx.z;
    const int t = threadIdx.x, l = t & 63, w = t >> 6;
    const int lq = l & 31, hf = l >> 5;
    const int sr = t >> 2, scol = (t & 3) * 16;           // staging row/col

    const unsigned short* Qb = Q + ((size_t)b * NH + h) * NS * ND;
    const unsigned short* Kp = K + ((size_t)b * NH + h) * NT * ND
                                 + (size_t)sr * ND + scol;
    const unsigned short* Vp = Vt + ((size_t)b * NH + h) * ND * NT
                                  + (size_t)sr * NT + scol;

    // Q B-frags (row q = s0 + w*32 + lq, k = ks*16 + hf*8), direct global
    short8 qf[4];
    {
        const unsigned short* qrow = Qb + (size_t)(s0 + w * 32 + lq) * ND + hf * 8;
        #pragma unroll
        for (int ks = 0; ks < 4; ++ks) qf[ks] = *(const short8*)(qrow + ks * 16);
    }

    f32x16 o0, o1;
    #pragma unroll
    for (int i = 0; i < 16; ++i) { o0[i] = 0.f; o1[i] = 0.f; }
    float rs = 0.f;

    union PFrag { unsigned dw[4]; short8 s8; };

    for (int t0 = 0; t0 < NT; t0 += 64) {
        *(short8*)&Ks[sr][scol]     = *(const short8*)(Kp);
        *(short8*)&Ks[sr][scol + 8] = *(const short8*)(Kp + 8);
        *(short8*)&Vs[sr][scol]     = *(const short8*)(Vp);
        *(short8*)&Vs[sr][scol + 8] = *(const short8*)(Vp + 8);
        Kp += 64 * ND; Vp += 64;
        __syncthreads();

        // S^T = K Q^T over d=64 (4 k-steps), two 32-kv tiles
        f32x16 sc0, sc1;
        #pragma unroll
        for (int i = 0; i < 16; ++i) { sc0[i] = 0.f; sc1[i] = 0.f; }
        __builtin_amdgcn_s_setprio(1);
        #pragma unroll
        for (int ks = 0; ks < 4; ++ks) {
            short8 kf0 = *(const short8*)&Ks[lq][ks * 16 + hf * 8];
            short8 kf1 = *(const short8*)&Ks[32 + lq][ks * 16 + hf * 8];
            sc0 = __builtin_amdgcn_mfma_f32_32x32x16_bf16(kf0, qf[ks], sc0, 0, 0, 0);
            sc1 = __builtin_amdgcn_mfma_f32_32x32x16_bf16(kf1, qf[ks], sc1, 0, 0, 0);
        }
        __builtin_amdgcn_s_setprio(0);

        // softmax (Q pre-scaled: p = exp2(s)) + in-register pack to A-frags
        PFrag pf[4];
        #pragma unroll
        for (int kvt = 0; kvt < 2; ++kvt) {
            float pp[16];
            #pragma unroll
            for (int i = 0; i < 16; ++i) {
                float s = kvt ? sc1[i] : sc0[i];
                pp[i] = __builtin_amdgcn_exp2f(s);
                rs += pp[i];
            }
            unsigned Pk[8];
            #pragma unroll
            for (int s4 = 0; s4 < 4; ++s4) {
                Pk[2 * s4]     = pkbf(pp[4 * s4],     pp[4 * s4 + 1]);
                Pk[2 * s4 + 1] = pkbf(pp[4 * s4 + 2], pp[4 * s4 + 3]);
            }
            #pragma unroll
            for (int d = 0; d < 2; ++d) {
                unsigned a0 = Pk[d],     b0 = Pk[2 + d];   // octets 0,1
                asm volatile("v_permlane32_swap_b32 %0, %1" : "+v"(a0), "+v"(b0));
                pf[kvt * 2].dw[d] = a0; pf[kvt * 2].dw[d + 2] = b0;
                unsigned a1 = Pk[4 + d], b1 = Pk[6 + d];   // octets 2,3
                asm volatile("v_permlane32_swap_b32 %0, %1" : "+v"(a1), "+v"(b1));
                pf[kvt * 2 + 1].dw[d] = a1; pf[kvt * 2 + 1].dw[d + 2] = b1;
            }
        }

        // O += P V  (A = P frags in regs, B = V^T rows; 4 kv k-steps x 2 d)
        __builtin_amdgcn_s_setprio(1);
        #pragma unroll
        for (int m = 0; m < 4; ++m) {
            short8 vf0 = *(const short8*)&Vs[lq][m * 16 + hf * 8];
            short8 vf1 = *(const short8*)&Vs[32 + lq][m * 16 + hf * 8];
            o0 = __builtin_amdgcn_mfma_f32_32x32x16_bf16(pf[m].s8, vf0, o0, 0, 0, 0);
            o1 = __builtin_amdgcn_mfma_f32_32x32x16_bf16(pf[m].s8, vf1, o1, 0, 0, 0);
        }
        __builtin_amdgcn_s_setprio(0);
        __syncthreads();
    }

    // full row sum for q=lq: own half + peer half; transpose via tiny LDS
    float tot = rs + __shfl_xor(rs, 32);
    Ss[w][lq] = tot;
    // epilogue: rows q = w*32 + crow(r,hf); cols d = dt*32 + lq
    #pragma unroll
    for (int r = 0; r < 16; ++r) {
        int ql = (r & 3) + 8 * (r >> 2) + 4 * hf;
        float inv = 1.f / Ss[w][ql];
        int srow2 = s0 + w * 32 + ql;
        size_t base = ((size_t)b * NS + srow2) * NE + h * ND + lq;
        Oc[base]      = f2bf(o0[r] * inv);
        Oc[base + 32] = f2bf(o1[r] * inv);
    }
}

extern "C" void kernel_launch(void* const* d_in, const int* in_sizes, int n_in,
                              void* d_out, int out_size, void* d_ws, size_t ws_size,
                              hipStream_t stream)
{
    const float* x  = (const float*)d_in[0];
    const float* y  = (const float*)d_in[1];
    const float* Wq = (const float*)d_in[2];
    const float* bq = (const float*)d_in[3];
    const float* Wk = (const float*)d_in[4];
    const float* bk = (const float*)d_in[5];
    const float* Wv = (const float*)d_in[6];
    const float* bv = (const float*)d_in[7];
    const float* Wo = (const float*)d_in[8];
    const float* bo = (const float*)d_in[9];
    float* out = (float*)d_out;

    // ws layout: xb | yb | WcT | qb | kb | vt | bc   (replay-safe aliases:
    //   cc -> yb (dead after K/V projection), WoT -> WcT rows 0..1023,
    //   woT_prep runs before flash)
    unsigned short* xb  = (unsigned short*)d_ws;             // NM*NE bf16
    unsigned short* yb  = xb + (size_t)NM * NE;
    unsigned short* WcT = yb + (size_t)NM * NE;              // 3072*NE bf16
    unsigned short* qb  = WcT + (size_t)3072 * NE;           // NM*NE bf16
    unsigned short* kb  = qb + (size_t)NM * NE;
    unsigned short* vt  = kb + (size_t)NM * NE;              // [B,H,D,T]
    float* bc = (float*)(vt + (size_t)NM * NE);              // 3072 fp32
    unsigned short* cc  = yb;                                // bf16 concat
    unsigned short* WoT = WcT;                               // 1024*1024 bf16

    const int n4 = NM * NE / 4;
    cvt_bf16<<<2048, 256, 0, stream>>>(x, xb, n4);
    cvt_bf16<<<2048, 256, 0, stream>>>(y, yb, n4);
    wqkv_prep<<<dim3(16, 48), 256, 0, stream>>>(Wq, Wk, Wv, WcT);
    bias_cat<<<4, 256, 0, stream>>>(bq, bk, bv, bc);

    gemm_qkv<<<dim3(64, 24), 256, 0, stream>>>(xb, yb, WcT, bc, qb, kb, vt);
    woT_prep<<<dim3(16, 16), 256, 0, stream>>>(Wo, WoT);
    flash_mfma<<<dim3(NS / 128, NH, NB), 256, 0, stream>>>(qb, kb, vt, cc);
    gemm_out<<<dim3(64, 8), 256, 0, stream>>>(cc, WoT, bo, out);
}

// Round 19
// 233.045 us; speedup vs baseline: 1.0032x; 1.0032x over previous
//
#include <hip/hip_runtime.h>
#include <hip/hip_bf16.h>
#include <cstddef>

#define NB 4
#define NS 2048
#define NT 2048
#define NE 1024
#define NH 16
#define ND 64
#define NM (NB*NS)   // 8192 rows

typedef __attribute__((ext_vector_type(8))) short short8;
typedef __attribute__((ext_vector_type(4))) float f32x4;
typedef __attribute__((ext_vector_type(16))) float f32x16;
typedef __attribute__((ext_vector_type(4))) unsigned short us4;
typedef __attribute__((ext_vector_type(8))) unsigned short us8;

__device__ __forceinline__ unsigned short f2bf(float f) {
    union { float f; unsigned u; } v; v.f = f;
    unsigned r = v.u + 0x7fffu + ((v.u >> 16) & 1u);
    return (unsigned short)(r >> 16);
}

// packed pair f32->bf16: native v_cvt_pk_bf16_f32 (no builtin on gfx950)
__device__ __forceinline__ unsigned pkbf(float a, float b) {
    unsigned r;
    asm("v_cvt_pk_bf16_f32 %0, %1, %2" : "=v"(r) : "v"(a), "v"(b));
    return r;
}

// async global->LDS, 16B per lane. LDS dest = wave-uniform base + lane*16.
__device__ __forceinline__ void gl16(const void* g, void* l) {
    __builtin_amdgcn_global_load_lds(
        (const __attribute__((address_space(1))) unsigned int*)g,
        (__attribute__((address_space(3))) unsigned int*)l,
        16, 0, 0);
}

// ---------------------------------------------------------------------------
// fp32 -> bf16 bulk convert (vectorized, grid-stride)
// ---------------------------------------------------------------------------
__global__ void cvt_bf16(const float* __restrict__ src,
                         unsigned short* __restrict__ dst, int n4)
{
    int i = blockIdx.x * blockDim.x + threadIdx.x;
    int stride = gridDim.x * blockDim.x;
    for (; i < n4; i += stride) {
        float4 v = ((const float4*)src)[i];
        us4 o;
        o[0] = f2bf(v.x); o[1] = f2bf(v.y); o[2] = f2bf(v.z); o[3] = f2bf(v.w);
        ((us4*)dst)[i] = o;
    }
}

// ---------------------------------------------------------------------------
// Wq/Wk/Wv [16][1024][64] fp32 -> WcT bf16 [3072][1024]  (B^T layout)
// ---------------------------------------------------------------------------
__global__ __launch_bounds__(256)
void wqkv_prep(const float* __restrict__ Wq, const float* __restrict__ Wk,
               const float* __restrict__ Wv, unsigned short* __restrict__ WcT)
{
    __shared__ float Ts[64][65];
    const int p = blockIdx.y;            // 0..47
    const int e0 = blockIdx.x * 64;
    const int j = p >> 4, h = p & 15;
    const float* W = (j == 0 ? Wq : (j == 1 ? Wk : Wv)) + (size_t)h * NE * ND;
    const int t = threadIdx.x;
    #pragma unroll
    for (int l = 0; l < 4; ++l) {
        int e = l * 16 + (t >> 4), d4 = (t & 15) * 4;
        float4 v = *(const float4*)(W + (size_t)(e0 + e) * ND + d4);
        Ts[d4 + 0][e] = v.x; Ts[d4 + 1][e] = v.y;
        Ts[d4 + 2][e] = v.z; Ts[d4 + 3][e] = v.w;
    }
    __syncthreads();
    const int d = t >> 2, c = (t & 3) * 16;
    us8 o0, o1;
    #pragma unroll
    for (int i = 0; i < 8; ++i) {
        o0[i] = f2bf(Ts[d][c + i]);
        o1[i] = f2bf(Ts[d][c + 8 + i]);
    }
    unsigned short* dst = WcT + ((size_t)(p * 64 + d)) * NE + e0 + c;
    *(us8*)dst = o0; *(us8*)(dst + 8) = o1;
}

// ---------------------------------------------------------------------------
// Wo [1024][1024] fp32 -> WoT bf16 [n][e] (transposed)
// ---------------------------------------------------------------------------
__global__ __launch_bounds__(256)
void woT_prep(const float* __restrict__ Wo, unsigned short* __restrict__ WoT)
{
    __shared__ float Ts[64][65];
    const int c0 = blockIdx.x * 64, n0 = blockIdx.y * 64;
    const int t = threadIdx.x;
    #pragma unroll
    for (int l = 0; l < 4; ++l) {
        int c = l * 16 + (t >> 4), n4 = (t & 15) * 4;
        float4 v = *(const float4*)(Wo + (size_t)(c0 + c) * NE + n0 + n4);
        Ts[n4 + 0][c] = v.x; Ts[n4 + 1][c] = v.y;
        Ts[n4 + 2][c] = v.z; Ts[n4 + 3][c] = v.w;
    }
    __syncthreads();
    const int n = t >> 2, cc4 = (t & 3) * 16;
    us8 o0, o1;
    #pragma unroll
    for (int i = 0; i < 8; ++i) {
        o0[i] = f2bf(Ts[n][cc4 + i]);
        o1[i] = f2bf(Ts[n][cc4 + 8 + i]);
    }
    unsigned short* dst = WoT + (size_t)(n0 + n) * NE + c0 + cc4;
    *(us8*)dst = o0; *(us8*)(dst + 8) = o1;
}

__global__ void bias_cat(const float* __restrict__ bq, const float* __restrict__ bk,
                         const float* __restrict__ bv, float* __restrict__ bc)
{
    int i = blockIdx.x * blockDim.x + threadIdx.x;
    if (i < 1024) { bc[i] = bq[i]; bc[1024 + i] = bk[i]; bc[2048 + i] = bv[i]; }
}

// ---------------------------------------------------------------------------
// FUSED QKV projection GEMM (kept from R16, verified: -6 us vs split).
// grid 64x24 = 1536 blocks ~ 6/CU. Block picks A = xb (Q) or yb (K/V).
// BK=64 / gl16 / slot^=row&7 staging (R12-verified).
// ---------------------------------------------------------------------------
__global__ __launch_bounds__(256)
void gemm_qkv(const unsigned short* __restrict__ xb,
              const unsigned short* __restrict__ yb,
              const unsigned short* __restrict__ WcT,
              const float* __restrict__ bias,
              unsigned short* __restrict__ qb, unsigned short* __restrict__ kb,
              unsigned short* __restrict__ vt)
{
    __shared__ __align__(16) unsigned short As[128 * 64];
    __shared__ __align__(16) unsigned short Bs[128 * 64];
    const int m0 = blockIdx.x * 128;
    const int gn0 = blockIdx.y * 128;            // global n offset 0..2944
    const unsigned short* A  = (gn0 < 1024) ? xb : yb;
    const unsigned short* Bt = WcT + (size_t)gn0 * NE;
    const int t = threadIdx.x, l = t & 63, w = t >> 6;
    const int wm = w >> 1, wn = w & 1;
    const int srow = l >> 3;
    const int sslot = (l & 7) ^ (srow & 7);
    const int rl = l & 15;
    const int q = l >> 4;

    const f32x4 fz = {0.f, 0.f, 0.f, 0.f};
    f32x4 acc[4][4];
    #pragma unroll
    for (int i = 0; i < 4; ++i)
        #pragma unroll
        for (int j = 0; j < 4; ++j) acc[i][j] = fz;

    for (int k0 = 0; k0 < NE; k0 += 64) {
        __syncthreads();
        #pragma unroll
        for (int j = 0; j < 4; ++j) {
            int ra = w * 32 + j * 8 + srow;
            gl16(A + (size_t)(m0 + ra) * NE + k0 + sslot * 8,
                 &As[(w * 32 + j * 8) * 64]);
            gl16(Bt + (size_t)ra * NE + k0 + sslot * 8,
                 &Bs[(w * 32 + j * 8) * 64]);
        }
        __syncthreads();
        #pragma unroll
        for (int kk = 0; kk < 2; ++kk) {
            const int fsl = ((kk * 4 + q) ^ (rl & 7)) * 8;
            short8 a[4], b[4];
            #pragma unroll
            for (int mi = 0; mi < 4; ++mi)
                a[mi] = *(const short8*)&As[(wm * 64 + mi * 16 + rl) * 64 + fsl];
            #pragma unroll
            for (int ni = 0; ni < 4; ++ni)
                b[ni] = *(const short8*)&Bs[(wn * 64 + ni * 16 + rl) * 64 + fsl];
            #pragma unroll
            for (int mi = 0; mi < 4; ++mi)
                #pragma unroll
                for (int ni = 0; ni < 4; ++ni)
                    acc[mi][ni] = __builtin_amdgcn_mfma_f32_16x16x32_bf16(
                        a[mi], b[ni], acc[mi][ni], 0, 0, 0);
        }
    }

    const float c1 = 0.18033688011112042f;   // 0.125 * log2(e)
    #pragma unroll
    for (int mi = 0; mi < 4; ++mi) {
        #pragma unroll
        for (int ni = 0; ni < 4; ++ni) {
            int n = gn0 + wn * 64 + ni * 16 + (l & 15);
            float bs = bias[n];
            int j = n >> 10, hh = (n >> 6) & 15, d = n & 63;
            float sc = (j == 0) ? c1 : 1.0f;
            #pragma unroll
            for (int r = 0; r < 4; ++r) {
                int i = m0 + wm * 64 + mi * 16 + (l >> 4) * 4 + r;
                int b = i >> 11, s = i & (NS - 1);
                unsigned short bfv = f2bf((acc[mi][ni][r] + bs) * sc);
                if (j == 0)
                    qb[(((size_t)b * NH + hh) * NS + s) * ND + d] = bfv;
                else if (j == 1)
                    kb[(((size_t)b * NH + hh) * NT + s) * ND + d] = bfv;
                else
                    vt[(((size_t)b * NH + hh) * ND + d) * NT + s] = bfv;
            }
        }
    }
}

// ---------------------------------------------------------------------------
// bf16 MFMA GEMM for output projection, v3: BM=128 x BN=64 tile, 4 waves
// stacked on M (each 32x64, acc[2][4]), grid 64x16 = 1024 blocks = 4/CU
// (old 128x128 tile was 512 blocks = 2/CU, grid-limited — same fix as the
// R16 QKV fusion). BK=64 / gl16 / slot^=row&7 staging unchanged (verified).
// ---------------------------------------------------------------------------
__global__ __launch_bounds__(256)
void gemm_out(const unsigned short* __restrict__ A,
              const unsigned short* __restrict__ Bt,
              const float* __restrict__ bias, float* __restrict__ C)
{
    __shared__ __align__(16) unsigned short As[128 * 64];
    __shared__ __align__(16) unsigned short Bs[64 * 64];
    const int m0 = blockIdx.x * 128, n0 = blockIdx.y * 64;
    const int t = threadIdx.x, l = t & 63, w = t >> 6;
    const int srow = l >> 3;
    const int sslot = (l & 7) ^ (srow & 7);
    const int rl = l & 15;
    const int q = l >> 4;

    const f32x4 fz = {0.f, 0.f, 0.f, 0.f};
    f32x4 acc[2][4];
    #pragma unroll
    for (int i = 0; i < 2; ++i)
        #pragma unroll
        for (int j = 0; j < 4; ++j) acc[i][j] = fz;

    for (int k0 = 0; k0 < NE; k0 += 64) {
        __syncthreads();
        #pragma unroll
        for (int j = 0; j < 4; ++j) {         // A: 128 rows, 32/wave
            int ra = w * 32 + j * 8 + srow;
            gl16(A + (size_t)(m0 + ra) * NE + k0 + sslot * 8,
                 &As[(w * 32 + j * 8) * 64]);
        }
        #pragma unroll
        for (int j = 0; j < 2; ++j) {         // B: 64 rows, 16/wave
            int rb = w * 16 + j * 8 + srow;
            gl16(Bt + (size_t)(n0 + rb) * NE + k0 + sslot * 8,
                 &Bs[(w * 16 + j * 8) * 64]);
        }
        __syncthreads();
        #pragma unroll
        for (int kk = 0; kk < 2; ++kk) {
            const int fsl = ((kk * 4 + q) ^ (rl & 7)) * 8;
            short8 a[2], b[4];
            #pragma unroll
            for (int mi = 0; mi < 2; ++mi)
                a[mi] = *(const short8*)&As[(w * 32 + mi * 16 + rl) * 64 + fsl];
            #pragma unroll
            for (int ni = 0; ni < 4; ++ni)
                b[ni] = *(const short8*)&Bs[(ni * 16 + rl) * 64 + fsl];
            #pragma unroll
            for (int mi = 0; mi < 2; ++mi)
                #pragma unroll
                for (int ni = 0; ni < 4; ++ni)
                    acc[mi][ni] = __builtin_amdgcn_mfma_f32_16x16x32_bf16(
                        a[mi], b[ni], acc[mi][ni], 0, 0, 0);
        }
    }

    #pragma unroll
    for (int mi = 0; mi < 2; ++mi) {
        #pragma unroll
        for (int ni = 0; ni < 4; ++ni) {
            int n = n0 + ni * 16 + (l & 15);
            float bs = bias[n];
            #pragma unroll
            for (int r = 0; r < 4; ++r) {
                int i = m0 + w * 32 + mi * 16 + (l >> 4) * 4 + r;
                C[(size_t)i * NE + n] = acc[mi][ni][r] + bs;
            }
        }
    }
}

// ---------------------------------------------------------------------------
// bf16 MFMA flash attention v4 + T5 setprio (kept from R18: per-dispatch
// verified 96.5 us vs 101, MfmaUtil 29.5->31.8)
// ---------------------------------------------------------------------------
__global__ __launch_bounds__(256)
void flash_mfma(const unsigned short* __restrict__ Q,
                const unsigned short* __restrict__ K,
                const unsigned short* __restrict__ Vt,
                unsigned short* __restrict__ Oc)
{
    __shared__ __align__(16) unsigned short Ks[64][72];
    __shared__ __align__(16) unsigned short Vs[64][72];   // V^T tile: [d][t]
    __shared__ float Ss[4][32];
    const int s0 = blockIdx.x * 128, h = blockIdx.y, b = blockIdx.z;
    const int t = threadIdx.x, l = t & 63, w = t >> 6;
    const int lq = l & 31, hf = l >> 5;
    const int sr = t >> 2, scol = (t & 3) * 16;           // staging row/col

    const unsigned short* Qb = Q + ((size_t)b * NH + h) * NS * ND;
    const unsigned short* Kp = K + ((size_t)b * NH + h) * NT * ND
                                 + (size_t)sr * ND + scol;
    const unsigned short* Vp = Vt + ((size_t)b * NH + h) * ND * NT
                                  + (size_t)sr * NT + scol;

    // Q B-frags (row q = s0 + w*32 + lq, k = ks*16 + hf*8), direct global
    short8 qf[4];
    {
        const unsigned short* qrow = Qb + (size_t)(s0 + w * 32 + lq) * ND + hf * 8;
        #pragma unroll
        for (int ks = 0; ks < 4; ++ks) qf[ks] = *(const short8*)(qrow + ks * 16);
    }

    f32x16 o0, o1;
    #pragma unroll
    for (int i = 0; i < 16; ++i) { o0[i] = 0.f; o1[i] = 0.f; }
    float rs = 0.f;

    union PFrag { unsigned dw[4]; short8 s8; };

    for (int t0 = 0; t0 < NT; t0 += 64) {
        *(short8*)&Ks[sr][scol]     = *(const short8*)(Kp);
        *(short8*)&Ks[sr][scol + 8] = *(const short8*)(Kp + 8);
        *(short8*)&Vs[sr][scol]     = *(const short8*)(Vp);
        *(short8*)&Vs[sr][scol + 8] = *(const short8*)(Vp + 8);
        Kp += 64 * ND; Vp += 64;
        __syncthreads();

        // S^T = K Q^T over d=64 (4 k-steps), two 32-kv tiles
        f32x16 sc0, sc1;
        #pragma unroll
        for (int i = 0; i < 16; ++i) { sc0[i] = 0.f; sc1[i] = 0.f; }
        __builtin_amdgcn_s_setprio(1);
        #pragma unroll
        for (int ks = 0; ks < 4; ++ks) {
            short8 kf0 = *(const short8*)&Ks[lq][ks * 16 + hf * 8];
            short8 kf1 = *(const short8*)&Ks[32 + lq][ks * 16 + hf * 8];
            sc0 = __builtin_amdgcn_mfma_f32_32x32x16_bf16(kf0, qf[ks], sc0, 0, 0, 0);
            sc1 = __builtin_amdgcn_mfma_f32_32x32x16_bf16(kf1, qf[ks], sc1, 0, 0, 0);
        }
        __builtin_amdgcn_s_setprio(0);

        // softmax (Q pre-scaled: p = exp2(s)) + in-register pack to A-frags
        PFrag pf[4];
        #pragma unroll
        for (int kvt = 0; kvt < 2; ++kvt) {
            float pp[16];
            #pragma unroll
            for (int i = 0; i < 16; ++i) {
                float s = kvt ? sc1[i] : sc0[i];
                pp[i] = __builtin_amdgcn_exp2f(s);
                rs += pp[i];
            }
            unsigned Pk[8];
            #pragma unroll
            for (int s4 = 0; s4 < 4; ++s4) {
                Pk[2 * s4]     = pkbf(pp[4 * s4],     pp[4 * s4 + 1]);
                Pk[2 * s4 + 1] = pkbf(pp[4 * s4 + 2], pp[4 * s4 + 3]);
            }
            #pragma unroll
            for (int d = 0; d < 2; ++d) {
                unsigned a0 = Pk[d],     b0 = Pk[2 + d];   // octets 0,1
                asm volatile("v_permlane32_swap_b32 %0, %1" : "+v"(a0), "+v"(b0));
                pf[kvt * 2].dw[d] = a0; pf[kvt * 2].dw[d + 2] = b0;
                unsigned a1 = Pk[4 + d], b1 = Pk[6 + d];   // octets 2,3
                asm volatile("v_permlane32_swap_b32 %0, %1" : "+v"(a1), "+v"(b1));
                pf[kvt * 2 + 1].dw[d] = a1; pf[kvt * 2 + 1].dw[d + 2] = b1;
            }
        }

        // O += P V  (A = P frags in regs, B = V^T rows; 4 kv k-steps x 2 d)
        __builtin_amdgcn_s_setprio(1);
        #pragma unroll
        for (int m = 0; m < 4; ++m) {
            short8 vf0 = *(const short8*)&Vs[lq][m * 16 + hf * 8];
            short8 vf1 = *(const short8*)&Vs[32 + lq][m * 16 + hf * 8];
            o0 = __builtin_amdgcn_mfma_f32_32x32x16_bf16(pf[m].s8, vf0, o0, 0, 0, 0);
            o1 = __builtin_amdgcn_mfma_f32_32x32x16_bf16(pf[m].s8, vf1, o1, 0, 0, 0);
        }
        __builtin_amdgcn_s_setprio(0);
        __syncthreads();
    }

    // full row sum for q=lq: own half + peer half; transpose via tiny LDS
    float tot = rs + __shfl_xor(rs, 32);
    Ss[w][lq] = tot;
    // epilogue: rows q = w*32 + crow(r,hf); cols d = dt*32 + lq
    #pragma unroll
    for (int r = 0; r < 16; ++r) {
        int ql = (r & 3) + 8 * (r >> 2) + 4 * hf;
        float inv = 1.f / Ss[w][ql];
        int srow2 = s0 + w * 32 + ql;
        size_t base = ((size_t)b * NS + srow2) * NE + h * ND + lq;
        Oc[base]      = f2bf(o0[r] * inv);
        Oc[base + 32] = f2bf(o1[r] * inv);
    }
}

extern "C" void kernel_launch(void* const* d_in, const int* in_sizes, int n_in,
                              void* d_out, int out_size, void* d_ws, size_t ws_size,
                              hipStream_t stream)
{
    const float* x  = (const float*)d_in[0];
    const float* y  = (const float*)d_in[1];
    const float* Wq = (const float*)d_in[2];
    const float* bq = (const float*)d_in[3];
    const float* Wk = (const float*)d_in[4];
    const float* bk = (const float*)d_in[5];
    const float* Wv = (const float*)d_in[6];
    const float* bv = (const float*)d_in[7];
    const float* Wo = (const float*)d_in[8];
    const float* bo = (const float*)d_in[9];
    float* out = (float*)d_out;

    // ws layout: xb | yb | WcT | qb | kb | vt | bc   (replay-safe aliases:
    //   cc -> yb (dead after K/V projection), WoT -> WcT rows 0..1023,
    //   woT_prep runs before flash)
    unsigned short* xb  = (unsigned short*)d_ws;             // NM*NE bf16
    unsigned short* yb  = xb + (size_t)NM * NE;
    unsigned short* WcT = yb + (size_t)NM * NE;              // 3072*NE bf16
    unsigned short* qb  = WcT + (size_t)3072 * NE;           // NM*NE bf16
    unsigned short* kb  = qb + (size_t)NM * NE;
    unsigned short* vt  = kb + (size_t)NM * NE;              // [B,H,D,T]
    float* bc = (float*)(vt + (size_t)NM * NE);              // 3072 fp32
    unsigned short* cc  = yb;                                // bf16 concat
    unsigned short* WoT = WcT;                               // 1024*1024 bf16

    const int n4 = NM * NE / 4;
    cvt_bf16<<<2048, 256, 0, stream>>>(x, xb, n4);
    cvt_bf16<<<2048, 256, 0, stream>>>(y, yb, n4);
    wqkv_prep<<<dim3(16, 48), 256, 0, stream>>>(Wq, Wk, Wv, WcT);
    bias_cat<<<4, 256, 0, stream>>>(bq, bk, bv, bc);

    gemm_qkv<<<dim3(64, 24), 256, 0, stream>>>(xb, yb, WcT, bc, qb, kb, vt);
    woT_prep<<<dim3(16, 16), 256, 0, stream>>>(Wo, WoT);
    flash_mfma<<<dim3(NS / 128, NH, NB), 256, 0, stream>>>(qb, kb, vt, cc);
    gemm_out<<<dim3(64, 16), 256, 0, stream>>>(cc, WoT, bo, out);
}

// Round 20
// 230.161 us; speedup vs baseline: 1.0158x; 1.0125x over previous
//
#include <hip/hip_runtime.h>
#include <hip/hip_bf16.h>
#include <cstddef>

#define NB 4
#define NS 2048
#define NT 2048
#define NE 1024
#define NH 16
#define ND 64
#define NM (NB*NS)   // 8192 rows

typedef __attribute__((ext_vector_type(8))) short short8;
typedef __attribute__((ext_vector_type(4))) float f32x4;
typedef __attribute__((ext_vector_type(16))) float f32x16;
typedef __attribute__((ext_vector_type(4))) unsigned short us4;
typedef __attribute__((ext_vector_type(8))) unsigned short us8;

__device__ __forceinline__ unsigned short f2bf(float f) {
    union { float f; unsigned u; } v; v.f = f;
    unsigned r = v.u + 0x7fffu + ((v.u >> 16) & 1u);
    return (unsigned short)(r >> 16);
}

// packed pair f32->bf16: native v_cvt_pk_bf16_f32 (no builtin on gfx950)
__device__ __forceinline__ unsigned pkbf(float a, float b) {
    unsigned r;
    asm("v_cvt_pk_bf16_f32 %0, %1, %2" : "=v"(r) : "v"(a), "v"(b));
    return r;
}

// async global->LDS, 16B per lane. LDS dest = wave-uniform base + lane*16.
__device__ __forceinline__ void gl16(const void* g, void* l) {
    __builtin_amdgcn_global_load_lds(
        (const __attribute__((address_space(1))) unsigned int*)g,
        (__attribute__((address_space(3))) unsigned int*)l,
        16, 0, 0);
}

// ---------------------------------------------------------------------------
// fp32 -> bf16 bulk convert, x and y in ONE launch (dst = xb|yb contiguous)
// ---------------------------------------------------------------------------
__global__ void cvt_bf16_xy(const float* __restrict__ x,
                            const float* __restrict__ y,
                            unsigned short* __restrict__ dst, int n4each)
{
    int i = blockIdx.x * blockDim.x + threadIdx.x;
    int stride = gridDim.x * blockDim.x;
    for (; i < 2 * n4each; i += stride) {
        float4 v = (i < n4each) ? ((const float4*)x)[i]
                                : ((const float4*)y)[i - n4each];
        us4 o;
        o[0] = f2bf(v.x); o[1] = f2bf(v.y); o[2] = f2bf(v.z); o[3] = f2bf(v.w);
        ((us4*)dst)[i] = o;
    }
}

// ---------------------------------------------------------------------------
// Wq/Wk/Wv [16][1024][64] fp32 -> WcT bf16 [3072][1024]  (B^T layout)
// + bias concat folded in (block e0==0 writes its panel's 64 bias entries)
// ---------------------------------------------------------------------------
__global__ __launch_bounds__(256)
void wqkv_prep(const float* __restrict__ Wq, const float* __restrict__ Wk,
               const float* __restrict__ Wv,
               const float* __restrict__ bq, const float* __restrict__ bk,
               const float* __restrict__ bv,
               unsigned short* __restrict__ WcT, float* __restrict__ bc)
{
    __shared__ float Ts[64][65];
    const int p = blockIdx.y;            // 0..47
    const int e0 = blockIdx.x * 64;
    const int j = p >> 4, h = p & 15;
    const float* W = (j == 0 ? Wq : (j == 1 ? Wk : Wv)) + (size_t)h * NE * ND;
    const int t = threadIdx.x;
    if (blockIdx.x == 0 && t < 64) {
        const float* bsrc = (j == 0 ? bq : (j == 1 ? bk : bv));
        bc[p * 64 + t] = bsrc[h * 64 + t];
    }
    #pragma unroll
    for (int l = 0; l < 4; ++l) {
        int e = l * 16 + (t >> 4), d4 = (t & 15) * 4;
        float4 v = *(const float4*)(W + (size_t)(e0 + e) * ND + d4);
        Ts[d4 + 0][e] = v.x; Ts[d4 + 1][e] = v.y;
        Ts[d4 + 2][e] = v.z; Ts[d4 + 3][e] = v.w;
    }
    __syncthreads();
    const int d = t >> 2, c = (t & 3) * 16;
    us8 o0, o1;
    #pragma unroll
    for (int i = 0; i < 8; ++i) {
        o0[i] = f2bf(Ts[d][c + i]);
        o1[i] = f2bf(Ts[d][c + 8 + i]);
    }
    unsigned short* dst = WcT + ((size_t)(p * 64 + d)) * NE + e0 + c;
    *(us8*)dst = o0; *(us8*)(dst + 8) = o1;
}

// ---------------------------------------------------------------------------
// Wo [1024][1024] fp32 -> WoT bf16 [n][e] (transposed)
// ---------------------------------------------------------------------------
__global__ __launch_bounds__(256)
void woT_prep(const float* __restrict__ Wo, unsigned short* __restrict__ WoT)
{
    __shared__ float Ts[64][65];
    const int c0 = blockIdx.x * 64, n0 = blockIdx.y * 64;
    const int t = threadIdx.x;
    #pragma unroll
    for (int l = 0; l < 4; ++l) {
        int c = l * 16 + (t >> 4), n4 = (t & 15) * 4;
        float4 v = *(const float4*)(Wo + (size_t)(c0 + c) * NE + n0 + n4);
        Ts[n4 + 0][c] = v.x; Ts[n4 + 1][c] = v.y;
        Ts[n4 + 2][c] = v.z; Ts[n4 + 3][c] = v.w;
    }
    __syncthreads();
    const int n = t >> 2, cc4 = (t & 3) * 16;
    us8 o0, o1;
    #pragma unroll
    for (int i = 0; i < 8; ++i) {
        o0[i] = f2bf(Ts[n][cc4 + i]);
        o1[i] = f2bf(Ts[n][cc4 + 8 + i]);
    }
    unsigned short* dst = WoT + (size_t)(n0 + n) * NE + c0 + cc4;
    *(us8*)dst = o0; *(us8*)(dst + 8) = o1;
}

// ---------------------------------------------------------------------------
// FUSED QKV projection GEMM (R16-verified). grid 64x24 ~ 6/CU.
// BK=64 / gl16 / slot^=row&7 staging.
// ---------------------------------------------------------------------------
__global__ __launch_bounds__(256)
void gemm_qkv(const unsigned short* __restrict__ xb,
              const unsigned short* __restrict__ yb,
              const unsigned short* __restrict__ WcT,
              const float* __restrict__ bias,
              unsigned short* __restrict__ qb, unsigned short* __restrict__ kb,
              unsigned short* __restrict__ vt)
{
    __shared__ __align__(16) unsigned short As[128 * 64];
    __shared__ __align__(16) unsigned short Bs[128 * 64];
    const int m0 = blockIdx.x * 128;
    const int gn0 = blockIdx.y * 128;            // global n offset 0..2944
    const unsigned short* A  = (gn0 < 1024) ? xb : yb;
    const unsigned short* Bt = WcT + (size_t)gn0 * NE;
    const int t = threadIdx.x, l = t & 63, w = t >> 6;
    const int wm = w >> 1, wn = w & 1;
    const int srow = l >> 3;
    const int sslot = (l & 7) ^ (srow & 7);
    const int rl = l & 15;
    const int q = l >> 4;

    const f32x4 fz = {0.f, 0.f, 0.f, 0.f};
    f32x4 acc[4][4];
    #pragma unroll
    for (int i = 0; i < 4; ++i)
        #pragma unroll
        for (int j = 0; j < 4; ++j) acc[i][j] = fz;

    for (int k0 = 0; k0 < NE; k0 += 64) {
        __syncthreads();
        #pragma unroll
        for (int j = 0; j < 4; ++j) {
            int ra = w * 32 + j * 8 + srow;
            gl16(A + (size_t)(m0 + ra) * NE + k0 + sslot * 8,
                 &As[(w * 32 + j * 8) * 64]);
            gl16(Bt + (size_t)ra * NE + k0 + sslot * 8,
                 &Bs[(w * 32 + j * 8) * 64]);
        }
        __syncthreads();
        #pragma unroll
        for (int kk = 0; kk < 2; ++kk) {
            const int fsl = ((kk * 4 + q) ^ (rl & 7)) * 8;
            short8 a[4], b[4];
            #pragma unroll
            for (int mi = 0; mi < 4; ++mi)
                a[mi] = *(const short8*)&As[(wm * 64 + mi * 16 + rl) * 64 + fsl];
            #pragma unroll
            for (int ni = 0; ni < 4; ++ni)
                b[ni] = *(const short8*)&Bs[(wn * 64 + ni * 16 + rl) * 64 + fsl];
            #pragma unroll
            for (int mi = 0; mi < 4; ++mi)
                #pragma unroll
                for (int ni = 0; ni < 4; ++ni)
                    acc[mi][ni] = __builtin_amdgcn_mfma_f32_16x16x32_bf16(
                        a[mi], b[ni], acc[mi][ni], 0, 0, 0);
        }
    }

    const float c1 = 0.18033688011112042f;   // 0.125 * log2(e)
    #pragma unroll
    for (int mi = 0; mi < 4; ++mi) {
        #pragma unroll
        for (int ni = 0; ni < 4; ++ni) {
            int n = gn0 + wn * 64 + ni * 16 + (l & 15);
            float bs = bias[n];
            int j = n >> 10, hh = (n >> 6) & 15, d = n & 63;
            float sc = (j == 0) ? c1 : 1.0f;
            #pragma unroll
            for (int r = 0; r < 4; ++r) {
                int i = m0 + wm * 64 + mi * 16 + (l >> 4) * 4 + r;
                int b = i >> 11, s = i & (NS - 1);
                unsigned short bfv = f2bf((acc[mi][ni][r] + bs) * sc);
                if (j == 0)
                    qb[(((size_t)b * NH + hh) * NS + s) * ND + d] = bfv;
                else if (j == 1)
                    kb[(((size_t)b * NH + hh) * NT + s) * ND + d] = bfv;
                else
                    vt[(((size_t)b * NH + hh) * ND + d) * NT + s] = bfv;
            }
        }
    }
}

// ---------------------------------------------------------------------------
// bf16 MFMA GEMM for output projection (R19: BM=128 x BN=64, 4/CU)
// ---------------------------------------------------------------------------
__global__ __launch_bounds__(256)
void gemm_out(const unsigned short* __restrict__ A,
              const unsigned short* __restrict__ Bt,
              const float* __restrict__ bias, float* __restrict__ C)
{
    __shared__ __align__(16) unsigned short As[128 * 64];
    __shared__ __align__(16) unsigned short Bs[64 * 64];
    const int m0 = blockIdx.x * 128, n0 = blockIdx.y * 64;
    const int t = threadIdx.x, l = t & 63, w = t >> 6;
    const int srow = l >> 3;
    const int sslot = (l & 7) ^ (srow & 7);
    const int rl = l & 15;
    const int q = l >> 4;

    const f32x4 fz = {0.f, 0.f, 0.f, 0.f};
    f32x4 acc[2][4];
    #pragma unroll
    for (int i = 0; i < 2; ++i)
        #pragma unroll
        for (int j = 0; j < 4; ++j) acc[i][j] = fz;

    for (int k0 = 0; k0 < NE; k0 += 64) {
        __syncthreads();
        #pragma unroll
        for (int j = 0; j < 4; ++j) {         // A: 128 rows, 32/wave
            int ra = w * 32 + j * 8 + srow;
            gl16(A + (size_t)(m0 + ra) * NE + k0 + sslot * 8,
                 &As[(w * 32 + j * 8) * 64]);
        }
        #pragma unroll
        for (int j = 0; j < 2; ++j) {         // B: 64 rows, 16/wave
            int rb = w * 16 + j * 8 + srow;
            gl16(Bt + (size_t)(n0 + rb) * NE + k0 + sslot * 8,
                 &Bs[(w * 16 + j * 8) * 64]);
        }
        __syncthreads();
        #pragma unroll
        for (int kk = 0; kk < 2; ++kk) {
            const int fsl = ((kk * 4 + q) ^ (rl & 7)) * 8;
            short8 a[2], b[4];
            #pragma unroll
            for (int mi = 0; mi < 2; ++mi)
                a[mi] = *(const short8*)&As[(w * 32 + mi * 16 + rl) * 64 + fsl];
            #pragma unroll
            for (int ni = 0; ni < 4; ++ni)
                b[ni] = *(const short8*)&Bs[(ni * 16 + rl) * 64 + fsl];
            #pragma unroll
            for (int mi = 0; mi < 2; ++mi)
                #pragma unroll
                for (int ni = 0; ni < 4; ++ni)
                    acc[mi][ni] = __builtin_amdgcn_mfma_f32_16x16x32_bf16(
                        a[mi], b[ni], acc[mi][ni], 0, 0, 0);
        }
    }

    #pragma unroll
    for (int mi = 0; mi < 2; ++mi) {
        #pragma unroll
        for (int ni = 0; ni < 4; ++ni) {
            int n = n0 + ni * 16 + (l & 15);
            float bs = bias[n];
            #pragma unroll
            for (int r = 0; r < 4; ++r) {
                int i = m0 + w * 32 + mi * 16 + (l >> 4) * 4 + r;
                C[(size_t)i * NE + n] = acc[mi][ni][r] + bs;
            }
        }
    }
}

// ---------------------------------------------------------------------------
// bf16 MFMA flash attention v4 + T5 setprio (R18-verified: 96.5 us)
// ---------------------------------------------------------------------------
__global__ __launch_bounds__(256)
void flash_mfma(const unsigned short* __restrict__ Q,
                const unsigned short* __restrict__ K,
                const unsigned short* __restrict__ Vt,
                unsigned short* __restrict__ Oc)
{
    __shared__ __align__(16) unsigned short Ks[64][72];
    __shared__ __align__(16) unsigned short Vs[64][72];   // V^T tile: [d][t]
    __shared__ float Ss[4][32];
    const int s0 = blockIdx.x * 128, h = blockIdx.y, b = blockIdx.z;
    const int t = threadIdx.x, l = t & 63, w = t >> 6;
    const int lq = l & 31, hf = l >> 5;
    const int sr = t >> 2, scol = (t & 3) * 16;           // staging row/col

    const unsigned short* Qb = Q + ((size_t)b * NH + h) * NS * ND;
    const unsigned short* Kp = K + ((size_t)b * NH + h) * NT * ND
                                 + (size_t)sr * ND + scol;
    const unsigned short* Vp = Vt + ((size_t)b * NH + h) * ND * NT
                                  + (size_t)sr * NT + scol;

    // Q B-frags (row q = s0 + w*32 + lq, k = ks*16 + hf*8), direct global
    short8 qf[4];
    {
        const unsigned short* qrow = Qb + (size_t)(s0 + w * 32 + lq) * ND + hf * 8;
        #pragma unroll
        for (int ks = 0; ks < 4; ++ks) qf[ks] = *(const short8*)(qrow + ks * 16);
    }

    f32x16 o0, o1;
    #pragma unroll
    for (int i = 0; i < 16; ++i) { o0[i] = 0.f; o1[i] = 0.f; }
    float rs = 0.f;

    union PFrag { unsigned dw[4]; short8 s8; };

    for (int t0 = 0; t0 < NT; t0 += 64) {
        *(short8*)&Ks[sr][scol]     = *(const short8*)(Kp);
        *(short8*)&Ks[sr][scol + 8] = *(const short8*)(Kp + 8);
        *(short8*)&Vs[sr][scol]     = *(const short8*)(Vp);
        *(short8*)&Vs[sr][scol + 8] = *(const short8*)(Vp + 8);
        Kp += 64 * ND; Vp += 64;
        __syncthreads();

        // S^T = K Q^T over d=64 (4 k-steps), two 32-kv tiles
        f32x16 sc0, sc1;
        #pragma unroll
        for (int i = 0; i < 16; ++i) { sc0[i] = 0.f; sc1[i] = 0.f; }
        __builtin_amdgcn_s_setprio(1);
        #pragma unroll
        for (int ks = 0; ks < 4; ++ks) {
            short8 kf0 = *(const short8*)&Ks[lq][ks * 16 + hf * 8];
            short8 kf1 = *(const short8*)&Ks[32 + lq][ks * 16 + hf * 8];
            sc0 = __builtin_amdgcn_mfma_f32_32x32x16_bf16(kf0, qf[ks], sc0, 0, 0, 0);
            sc1 = __builtin_amdgcn_mfma_f32_32x32x16_bf16(kf1, qf[ks], sc1, 0, 0, 0);
        }
        __builtin_amdgcn_s_setprio(0);

        // softmax (Q pre-scaled: p = exp2(s)) + in-register pack to A-frags
        PFrag pf[4];
        #pragma unroll
        for (int kvt = 0; kvt < 2; ++kvt) {
            float pp[16];
            #pragma unroll
            for (int i = 0; i < 16; ++i) {
                float s = kvt ? sc1[i] : sc0[i];
                pp[i] = __builtin_amdgcn_exp2f(s);
                rs += pp[i];
            }
            unsigned Pk[8];
            #pragma unroll
            for (int s4 = 0; s4 < 4; ++s4) {
                Pk[2 * s4]     = pkbf(pp[4 * s4],     pp[4 * s4 + 1]);
                Pk[2 * s4 + 1] = pkbf(pp[4 * s4 + 2], pp[4 * s4 + 3]);
            }
            #pragma unroll
            for (int d = 0; d < 2; ++d) {
                unsigned a0 = Pk[d],     b0 = Pk[2 + d];   // octets 0,1
                asm volatile("v_permlane32_swap_b32 %0, %1" : "+v"(a0), "+v"(b0));
                pf[kvt * 2].dw[d] = a0; pf[kvt * 2].dw[d + 2] = b0;
                unsigned a1 = Pk[4 + d], b1 = Pk[6 + d];   // octets 2,3
                asm volatile("v_permlane32_swap_b32 %0, %1" : "+v"(a1), "+v"(b1));
                pf[kvt * 2 + 1].dw[d] = a1; pf[kvt * 2 + 1].dw[d + 2] = b1;
            }
        }

        // O += P V  (A = P frags in regs, B = V^T rows; 4 kv k-steps x 2 d)
        __builtin_amdgcn_s_setprio(1);
        #pragma unroll
        for (int m = 0; m < 4; ++m) {
            short8 vf0 = *(const short8*)&Vs[lq][m * 16 + hf * 8];
            short8 vf1 = *(const short8*)&Vs[32 + lq][m * 16 + hf * 8];
            o0 = __builtin_amdgcn_mfma_f32_32x32x16_bf16(pf[m].s8, vf0, o0, 0, 0, 0);
            o1 = __builtin_amdgcn_mfma_f32_32x32x16_bf16(pf[m].s8, vf1, o1, 0, 0, 0);
        }
        __builtin_amdgcn_s_setprio(0);
        __syncthreads();
    }

    // full row sum for q=lq: own half + peer half; transpose via tiny LDS
    float tot = rs + __shfl_xor(rs, 32);
    Ss[w][lq] = tot;
    // epilogue: rows q = w*32 + crow(r,hf); cols d = dt*32 + lq
    #pragma unroll
    for (int r = 0; r < 16; ++r) {
        int ql = (r & 3) + 8 * (r >> 2) + 4 * hf;
        float inv = 1.f / Ss[w][ql];
        int srow2 = s0 + w * 32 + ql;
        size_t base = ((size_t)b * NS + srow2) * NE + h * ND + lq;
        Oc[base]      = f2bf(o0[r] * inv);
        Oc[base + 32] = f2bf(o1[r] * inv);
    }
}

extern "C" void kernel_launch(void* const* d_in, const int* in_sizes, int n_in,
                              void* d_out, int out_size, void* d_ws, size_t ws_size,
                              hipStream_t stream)
{
    const float* x  = (const float*)d_in[0];
    const float* y  = (const float*)d_in[1];
    const float* Wq = (const float*)d_in[2];
    const float* bq = (const float*)d_in[3];
    const float* Wk = (const float*)d_in[4];
    const float* bk = (const float*)d_in[5];
    const float* Wv = (const float*)d_in[6];
    const float* bv = (const float*)d_in[7];
    const float* Wo = (const float*)d_in[8];
    const float* bo = (const float*)d_in[9];
    float* out = (float*)d_out;

    // ws layout: xb | yb | WcT | qb | kb | vt | bc   (replay-safe aliases:
    //   cc -> yb (dead after K/V projection), WoT -> WcT rows 0..1023,
    //   woT_prep runs before flash)
    unsigned short* xb  = (unsigned short*)d_ws;             // NM*NE bf16
    unsigned short* yb  = xb + (size_t)NM * NE;
    unsigned short* WcT = yb + (size_t)NM * NE;              // 3072*NE bf16
    unsigned short* qb  = WcT + (size_t)3072 * NE;           // NM*NE bf16
    unsigned short* kb  = qb + (size_t)NM * NE;
    unsigned short* vt  = kb + (size_t)NM * NE;              // [B,H,D,T]
    float* bc = (float*)(vt + (size_t)NM * NE);              // 3072 fp32
    unsigned short* cc  = yb;                                // bf16 concat
    unsigned short* WoT = WcT;                               // 1024*1024 bf16

    const int n4 = NM * NE / 4;
    cvt_bf16_xy<<<2048, 256, 0, stream>>>(x, y, xb, n4);
    wqkv_prep<<<dim3(16, 48), 256, 0, stream>>>(Wq, Wk, Wv, bq, bk, bv, WcT, bc);

    gemm_qkv<<<dim3(64, 24), 256, 0, stream>>>(xb, yb, WcT, bc, qb, kb, vt);
    woT_prep<<<dim3(16, 16), 256, 0, stream>>>(Wo, WoT);
    flash_mfma<<<dim3(NS / 128, NH, NB), 256, 0, stream>>>(qb, kb, vt, cc);
    gemm_out<<<dim3(64, 16), 256, 0, stream>>>(cc, WoT, bo, out);
}